// Round 1
// baseline (924.175 us; speedup 1.0000x reference)
//
#include <hip/hip_runtime.h>

typedef _Float16 half8 __attribute__((ext_vector_type(8)));
typedef float    f32x4 __attribute__((ext_vector_type(4)));
typedef float    f32x2 __attribute__((ext_vector_type(2)));

#define TMASK ((1u << 19) - 1u)       // T = 2^19
#define HSTRIDE 136                    // 128 + 8 f16 pad (stride 272B -> ~2-way LDS conflicts)
constexpr float SCALE = 65536.0f;      // activation scale: keeps f16 out of subnormal range
constexpr float INV_SCALE = 1.0f / 65536.0f;

// ---------------------------------------------------------------------------
// Prep: rearrange fp32 weights into B-fragment-native f16 layout in d_ws.
// Tile layout: [tile][lane(64)][8 f16]; tile = layerOff + nt*KT + kt.
// B-frag mapping (16x16x32): n = nt*16 + (lane&15), k = kt*32 + (lane>>4)*8 + j.
// Tiles: W0: 0..7 (K=32), W1: 8..39, W2: 40..71, W3: 72..103, Wout(pad N->16): 104..107.
// Biases (f32, pre-scaled by S) at byte offset 110592: b0..b3 (4*128), bout (16, padded).
// ---------------------------------------------------------------------------
__global__ void prep_kernel(const float* __restrict__ W0, const float* __restrict__ W1,
                            const float* __restrict__ W2, const float* __restrict__ W3,
                            const float* __restrict__ Wm,
                            const float* __restrict__ b0, const float* __restrict__ b1,
                            const float* __restrict__ b2, const float* __restrict__ b3,
                            const float* __restrict__ bm,
                            _Float16* __restrict__ wsW, float* __restrict__ wsB)
{
    int gid = blockIdx.x * 256 + threadIdx.x;
    if (gid < 6912) {                       // 108 tiles * 64 lanes
        int tile = gid >> 6, lane = gid & 63;
        const float* W; int K, N, toff;
        if (tile < 8)        { W = W0; K = 32;  N = 128; toff = 0;   }
        else if (tile < 40)  { W = W1; K = 128; N = 128; toff = 8;   }
        else if (tile < 72)  { W = W2; K = 128; N = 128; toff = 40;  }
        else if (tile < 104) { W = W3; K = 128; N = 128; toff = 72;  }
        else                 { W = Wm; K = 128; N = 4;   toff = 104; }
        int tt = tile - toff;
        int KT = K >> 5;
        int nt = tt / KT, kt = tt - nt * KT;
        int n = nt * 16 + (lane & 15);
        int kbase = kt * 32 + (lane >> 4) * 8;
        half8 v;
        #pragma unroll
        for (int j = 0; j < 8; j++) {
            int k = kbase + j;
            float w = (n < N) ? W[k * N + n] : 0.0f;
            v[j] = (_Float16)w;
        }
        *(half8*)(wsW + (size_t)gid * 8) = v;
    } else if (gid < 6912 + 528) {
        int i = gid - 6912;
        float v;
        if (i < 512) {
            int layer = i >> 7, n = i & 127;
            const float* b = (layer == 0) ? b0 : (layer == 1) ? b1 : (layer == 2) ? b2 : b3;
            v = b[n] * SCALE;
        } else {
            int n = i - 512;
            v = (n < 4) ? bm[n] * SCALE : 0.0f;
        }
        wsB[i] = v;
    }
}

// ---------------------------------------------------------------------------
// One MLP layer, per-wave, in-place on LDS activations.
// Wave owns rows m0..m0+31 (reads only them, writes only them -> no barrier).
// A-frag (verified m89/m91): A[m = lane&15][k = (lane>>4)*8 + j]
// C/D    (verified m89):     col = lane&15, row = (lane>>4)*4 + reg
// ---------------------------------------------------------------------------
template<int KT, int TOFF, bool RELU>
__device__ __forceinline__ void mlp_layer(_Float16* h, const half8* __restrict__ wf,
                                          const float* __restrict__ wsB, int layerIdx,
                                          int m0, int lane)
{
    const int col = lane & 15, quad = lane >> 4;
    half8 a[2][KT];
    #pragma unroll
    for (int mt = 0; mt < 2; mt++)
        #pragma unroll
        for (int kt = 0; kt < KT; kt++)
            a[mt][kt] = *(const half8*)&h[(m0 + mt * 16 + col) * HSTRIDE + kt * 32 + quad * 8];

    f32x4 acc[2][8];
    #pragma unroll
    for (int nt = 0; nt < 8; nt++) {
        float bv = wsB[layerIdx * 128 + nt * 16 + col];
        acc[0][nt] = (f32x4){bv, bv, bv, bv};
        acc[1][nt] = (f32x4){bv, bv, bv, bv};
    }
    #pragma unroll
    for (int nt = 0; nt < 8; nt++) {
        half8 b[KT];
        #pragma unroll
        for (int kt = 0; kt < KT; kt++)
            b[kt] = wf[(size_t)(TOFF + nt * KT + kt) * 64 + lane];   // L2-hot global
        #pragma unroll
        for (int mt = 0; mt < 2; mt++)
            #pragma unroll
            for (int kt = 0; kt < KT; kt++)
                acc[mt][nt] = __builtin_amdgcn_mfma_f32_16x16x32_f16(a[mt][kt], b[kt], acc[mt][nt], 0, 0, 0);
    }
    // epilogue: bias already in acc; ReLU; f16 scatter back to row-major acts
    #pragma unroll
    for (int mt = 0; mt < 2; mt++)
        #pragma unroll
        for (int nt = 0; nt < 8; nt++) {
            f32x4 v = acc[mt][nt];
            #pragma unroll
            for (int r = 0; r < 4; r++) {
                float x = v[r];
                if (RELU) x = fmaxf(x, 0.0f);
                h[(m0 + mt * 16 + quad * 4 + r) * HSTRIDE + nt * 16 + col] = (_Float16)x;
            }
        }
}

__global__ __launch_bounds__(256, 2) void fused_kernel(
    const float* __restrict__ pos, const float* __restrict__ bmn, const float* __restrict__ bmx,
    const float* __restrict__ tables, const half8* __restrict__ wf, const float* __restrict__ wsB,
    float* __restrict__ out)
{
    __shared__ _Float16 hbuf[128 * HSTRIDE];
    __shared__ float outstage[512];
    const int t = threadIdx.x;
    const long base = (long)blockIdx.x * 128;

    // ---- hash-grid encode: 2 threads/point, 8 levels each ----
    {
        const int p = t >> 1, hh = t & 1;
        const long gp = base + p;
        const float b0x = bmn[0], b0y = bmn[1], b0z = bmn[2];
        const float nx = (pos[gp * 3 + 0] - b0x) / (bmx[0] - b0x);
        const float ny = (pos[gp * 3 + 1] - b0y) / (bmx[1] - b0y);
        const float nz = (pos[gp * 3 + 2] - b0z) / (bmx[2] - b0z);
        // floor(16 * 2^(l/3)) for l=0..15 (matches np float64 computation)
        constexpr float RLO[8] = {16.f, 20.f, 25.f, 32.f, 40.f, 50.f, 64.f, 80.f};
        constexpr float RHI[8] = {101.f, 128.f, 161.f, 203.f, 256.f, 322.f, 406.f, 512.f};
        half8 fa, fb;
        #pragma unroll
        for (int li = 0; li < 8; li++) {
            const float res = hh ? RHI[li] : RLO[li];
            const float* tbl = tables + ((size_t)(hh * 8 + li) << 20);   // l * T * 2 floats
            float xs = nx * res, ys = ny * res, zs = nz * res;
            float fx = floorf(xs), fy = floorf(ys), fz = floorf(zs);
            unsigned xi = (unsigned)fx, yi = (unsigned)fy, zi = (unsigned)fz;
            float tx = xs - fx, ty = ys - fy, tz = zs - fz;
            unsigned hx[2] = {xi, xi + 1u};
            unsigned hy[2] = {yi * 2654435761u, (yi + 1u) * 2654435761u};
            unsigned hz[2] = {zi * 805459861u, (zi + 1u) * 805459861u};
            float wx[2] = {1.0f - tx, tx}, wy[2] = {1.0f - ty, ty}, wz[2] = {1.0f - tz, tz};
            float a0 = 0.0f, a1 = 0.0f;
            #pragma unroll
            for (int c = 0; c < 8; c++) {
                unsigned hsh = hx[c & 1] ^ hy[(c >> 1) & 1] ^ hz[c >> 2];
                unsigned idx = hsh & TMASK;
                f32x2 f = *(const f32x2*)(tbl + (size_t)idx * 2);
                float w = wx[c & 1] * wy[(c >> 1) & 1] * wz[c >> 2];
                a0 += w * f.x;
                a1 += w * f.y;
            }
            if (li < 4) { fa[2 * li]       = (_Float16)(a0 * SCALE); fa[2 * li + 1]       = (_Float16)(a1 * SCALE); }
            else        { fb[2 * (li - 4)] = (_Float16)(a0 * SCALE); fb[2 * (li - 4) + 1] = (_Float16)(a1 * SCALE); }
        }
        // wave w's threads cover points 32w..32w+31 == its MLP rows (wave-private)
        *(half8*)&hbuf[p * HSTRIDE + hh * 16]     = fa;
        *(half8*)&hbuf[p * HSTRIDE + hh * 16 + 8] = fb;
    }
    __syncthreads();

    // ---- fused MLP, per-wave in-place (no inter-layer barriers) ----
    const int lane = t & 63;
    const int m0 = (t >> 6) * 32;
    mlp_layer<1, 0,   true>(hbuf, wf, wsB, 0, m0, lane);   // 32 -> 128
    mlp_layer<4, 8,   true>(hbuf, wf, wsB, 1, m0, lane);   // 128 -> 128
    mlp_layer<4, 40,  true>(hbuf, wf, wsB, 2, m0, lane);   // 128 -> 128
    mlp_layer<4, 72,  true>(hbuf, wf, wsB, 3, m0, lane);   // 128 -> 128
    {   // output layer: 128 -> 4 (padded to 16 cols), no ReLU
        const int col = lane & 15, quad = lane >> 4;
        half8 a[2][4];
        #pragma unroll
        for (int mt = 0; mt < 2; mt++)
            #pragma unroll
            for (int kt = 0; kt < 4; kt++)
                a[mt][kt] = *(const half8*)&hbuf[(m0 + mt * 16 + col) * HSTRIDE + kt * 32 + quad * 8];
        float bv = wsB[512 + col];
        f32x4 acc[2] = {(f32x4){bv, bv, bv, bv}, (f32x4){bv, bv, bv, bv}};
        half8 b[4];
        #pragma unroll
        for (int kt = 0; kt < 4; kt++)
            b[kt] = wf[(size_t)(104 + kt) * 64 + lane];
        #pragma unroll
        for (int mt = 0; mt < 2; mt++)
            #pragma unroll
            for (int kt = 0; kt < 4; kt++)
                acc[mt] = __builtin_amdgcn_mfma_f32_16x16x32_f16(a[mt][kt], b[kt], acc[mt], 0, 0, 0);
        if (col < 4) {
            #pragma unroll
            for (int mt = 0; mt < 2; mt++)
                #pragma unroll
                for (int r = 0; r < 4; r++)
                    outstage[(m0 + mt * 16 + quad * 4 + r) * 4 + col] = acc[mt][r] * INV_SCALE;
        }
    }
    __syncthreads();
    if (t < 128) {
        f32x4 v = ((const f32x4*)outstage)[t];
        *(f32x4*)(out + (base + t) * 4) = v;
    }
}

extern "C" void kernel_launch(void* const* d_in, const int* in_sizes, int n_in,
                              void* d_out, int out_size, void* d_ws, size_t ws_size,
                              hipStream_t stream) {
    const float* pos    = (const float*)d_in[0];
    const float* bmn    = (const float*)d_in[1];
    const float* bmx    = (const float*)d_in[2];
    const float* tables = (const float*)d_in[3];
    const float* W0 = (const float*)d_in[4];
    const float* b0 = (const float*)d_in[5];
    const float* W1 = (const float*)d_in[6];
    const float* b1 = (const float*)d_in[7];
    const float* W2 = (const float*)d_in[8];
    const float* b2 = (const float*)d_in[9];
    const float* W3 = (const float*)d_in[10];
    const float* b3 = (const float*)d_in[11];
    const float* Wm = (const float*)d_in[12];
    const float* bm = (const float*)d_in[13];

    _Float16* wsW = (_Float16*)d_ws;
    float* wsB = (float*)((char*)d_ws + 110592);   // 6912 frags * 16B

    const int N = in_sizes[0] / 3;
    prep_kernel<<<30, 256, 0, stream>>>(W0, W1, W2, W3, Wm, b0, b1, b2, b3, bm, wsW, wsB);
    fused_kernel<<<N / 128, 256, 0, stream>>>(pos, bmn, bmx, tables,
                                              (const half8*)d_ws, wsB, (float*)d_out);
}

// Round 2
// 815.557 us; speedup vs baseline: 1.1332x; 1.1332x over previous
//
#include <hip/hip_runtime.h>

typedef _Float16 half8 __attribute__((ext_vector_type(8)));
typedef _Float16 half4 __attribute__((ext_vector_type(4)));
typedef _Float16 half2 __attribute__((ext_vector_type(2)));
typedef float    f32x4 __attribute__((ext_vector_type(4)));
typedef float    f32x2 __attribute__((ext_vector_type(2)));

#define TMASK ((1u << 19) - 1u)       // T = 2^19
#define HSTRIDE 136                    // 128 + 8 f16 pad; 272B row stride (16B-aligned)
constexpr float SCALE = 65536.0f;      // activation scale: keeps f16 out of subnormal range
constexpr float INV_SCALE = 1.0f / 65536.0f;

// ---------------------------------------------------------------------------
// Prep: (a) convert fp32 tables -> f16 pre-scaled by SCALE (tabBlocks blocks),
//       (b) rearrange fp32 weights into B-fragment-native f16 layout + biases.
// Weight tile layout: [tile][lane(64)][8 f16]; B-frag (16x16x32):
//   n = nt*16 + (lane&15), k = kt*32 + (lane>>4)*8 + j.
// Tiles: W0:0..7, W1:8..39, W2:40..71, W3:72..103, Wout(pad N->16):104..107.
// ---------------------------------------------------------------------------
__global__ void prep_kernel(const float* __restrict__ W0, const float* __restrict__ W1,
                            const float* __restrict__ W2, const float* __restrict__ W3,
                            const float* __restrict__ Wm,
                            const float* __restrict__ b0, const float* __restrict__ b1,
                            const float* __restrict__ b2, const float* __restrict__ b3,
                            const float* __restrict__ bm,
                            _Float16* __restrict__ wsW, float* __restrict__ wsB,
                            const float* __restrict__ tables, _Float16* __restrict__ tabF,
                            int tabBlocks)
{
    if ((int)blockIdx.x < tabBlocks) {
        // table conversion: one thread per 4 floats; 16.8M floats total
        size_t i = (size_t)blockIdx.x * 256 + threadIdx.x;
        f32x4 v = ((const f32x4*)tables)[i];
        half4 o;
        o[0] = (_Float16)(v.x * SCALE);
        o[1] = (_Float16)(v.y * SCALE);
        o[2] = (_Float16)(v.z * SCALE);
        o[3] = (_Float16)(v.w * SCALE);
        ((half4*)tabF)[i] = o;
        return;
    }
    int gid = ((int)blockIdx.x - tabBlocks) * 256 + threadIdx.x;
    if (gid < 6912) {                       // 108 tiles * 64 lanes
        int tile = gid >> 6, lane = gid & 63;
        const float* W; int K, N, toff;
        if (tile < 8)        { W = W0; K = 32;  N = 128; toff = 0;   }
        else if (tile < 40)  { W = W1; K = 128; N = 128; toff = 8;   }
        else if (tile < 72)  { W = W2; K = 128; N = 128; toff = 40;  }
        else if (tile < 104) { W = W3; K = 128; N = 128; toff = 72;  }
        else                 { W = Wm; K = 128; N = 4;   toff = 104; }
        int tt = tile - toff;
        int KT = K >> 5;
        int nt = tt / KT, kt = tt - nt * KT;
        int n = nt * 16 + (lane & 15);
        int kbase = kt * 32 + (lane >> 4) * 8;
        half8 v;
        #pragma unroll
        for (int j = 0; j < 8; j++) {
            int k = kbase + j;
            float w = (n < N) ? W[k * N + n] : 0.0f;
            v[j] = (_Float16)w;
        }
        *(half8*)(wsW + (size_t)gid * 8) = v;
    } else if (gid < 6912 + 528) {
        int i = gid - 6912;
        float v;
        if (i < 512) {
            int layer = i >> 7, n = i & 127;
            const float* b = (layer == 0) ? b0 : (layer == 1) ? b1 : (layer == 2) ? b2 : b3;
            v = b[n] * SCALE;
        } else {
            int n = i - 512;
            v = (n < 4) ? bm[n] * SCALE : 0.0f;
        }
        wsB[i] = v;
    }
}

// ---------------------------------------------------------------------------
// Encode kernel, level-major with XCD affinity. Block handles 256 points for
// levels {lvl0, lvl0+8}; lvl0 = bid & 7 so (given round-robin bid%8 -> XCD)
// each XCD's L2 only holds its own coarse+fine table pair (<= 4 MB in f16).
// Feature writes are nontemporal so they don't evict the resident tables.
// ---------------------------------------------------------------------------
__global__ __launch_bounds__(256, 8) void encode_kernel(
    const float* __restrict__ pos, const float* __restrict__ bmn, const float* __restrict__ bmx,
    const _Float16* __restrict__ tab, _Float16* __restrict__ feat, int npts)
{
    const int lvl0 = (int)(blockIdx.x & 7);
    const int p = (int)(blockIdx.x >> 3) * 256 + (int)threadIdx.x;
    const float bx = bmn[0], by = bmn[1], bz = bmn[2];
    const float nx = (pos[(size_t)p * 3 + 0] - bx) / (bmx[0] - bx);
    const float ny = (pos[(size_t)p * 3 + 1] - by) / (bmx[1] - by);
    const float nz = (pos[(size_t)p * 3 + 2] - bz) / (bmx[2] - bz);
    constexpr float RESL[16] = {16.f, 20.f, 25.f, 32.f, 40.f, 50.f, 64.f, 80.f,
                                101.f, 128.f, 161.f, 203.f, 256.f, 322.f, 406.f, 512.f};
    #pragma unroll
    for (int s2 = 0; s2 < 2; s2++) {
        const int l = lvl0 + 8 * s2;
        const float res = RESL[l];
        const _Float16* tbl = tab + ((size_t)l << 20);   // T*2 f16 per level
        float xs = nx * res, ys = ny * res, zs = nz * res;
        float fx = floorf(xs), fy = floorf(ys), fz = floorf(zs);
        unsigned xi = (unsigned)fx, yi = (unsigned)fy, zi = (unsigned)fz;
        float tx = xs - fx, ty = ys - fy, tz = zs - fz;
        unsigned hx[2] = {xi, xi + 1u};
        unsigned hy[2] = {yi * 2654435761u, (yi + 1u) * 2654435761u};
        unsigned hz[2] = {zi * 805459861u, (zi + 1u) * 805459861u};
        half2 fv[8];
        #pragma unroll
        for (int c = 0; c < 8; c++) {
            unsigned idx = (hx[c & 1] ^ hy[(c >> 1) & 1] ^ hz[c >> 2]) & TMASK;
            fv[c] = *(const half2*)(tbl + (size_t)idx * 2);
        }
        float wx[2] = {1.0f - tx, tx}, wy[2] = {1.0f - ty, ty}, wz[2] = {1.0f - tz, tz};
        float a0 = 0.0f, a1 = 0.0f;
        #pragma unroll
        for (int c = 0; c < 8; c++) {
            float w = wx[c & 1] * wy[(c >> 1) & 1] * wz[c >> 2];
            a0 += w * (float)fv[c][0];
            a1 += w * (float)fv[c][1];
        }
        half2 o; o[0] = (_Float16)a0; o[1] = (_Float16)a1;
        union { half2 h; unsigned u; } cv; cv.h = o;
        __builtin_nontemporal_store(cv.u, (unsigned*)(feat + ((size_t)l * npts + p) * 2));
    }
}

// ---------------------------------------------------------------------------
// One MLP layer, per-wave, in-place on LDS activations (XOR-swizzled columns:
// f16 column c of row p lives at c ^ ((p&3)<<3) — kills staging bank conflicts
// while keeping half8 runs contiguous and 16B-aligned).
// A-frag: A[m=lane&15][k=(lane>>4)*8+j]; C/D: col=lane&15, row=(lane>>4)*4+reg.
// ---------------------------------------------------------------------------
template<int KT, int TOFF, bool RELU>
__device__ __forceinline__ void mlp_layer(_Float16* h, const half8* __restrict__ wf,
                                          const float* __restrict__ wsB, int layerIdx,
                                          int m0, int lane)
{
    const int col = lane & 15, quad = lane >> 4;
    const int sw = (col & 3) << 3;
    half8 a[2][KT];
    #pragma unroll
    for (int mt = 0; mt < 2; mt++)
        #pragma unroll
        for (int kt = 0; kt < KT; kt++)
            a[mt][kt] = *(const half8*)&h[(m0 + mt * 16 + col) * HSTRIDE + ((kt * 32 + quad * 8) ^ sw)];

    f32x4 acc[2][8];
    #pragma unroll
    for (int nt = 0; nt < 8; nt++) {
        float bv = wsB[layerIdx * 128 + nt * 16 + col];
        acc[0][nt] = (f32x4){bv, bv, bv, bv};
        acc[1][nt] = (f32x4){bv, bv, bv, bv};
    }
    #pragma unroll
    for (int nt = 0; nt < 8; nt++) {
        half8 b[KT];
        #pragma unroll
        for (int kt = 0; kt < KT; kt++)
            b[kt] = wf[(size_t)(TOFF + nt * KT + kt) * 64 + lane];   // L2-hot global
        #pragma unroll
        for (int mt = 0; mt < 2; mt++)
            #pragma unroll
            for (int kt = 0; kt < KT; kt++)
                acc[mt][nt] = __builtin_amdgcn_mfma_f32_16x16x32_f16(a[mt][kt], b[kt], acc[mt][nt], 0, 0, 0);
    }
    #pragma unroll
    for (int mt = 0; mt < 2; mt++)
        #pragma unroll
        for (int nt = 0; nt < 8; nt++) {
            f32x4 v = acc[mt][nt];
            #pragma unroll
            for (int r = 0; r < 4; r++) {
                float x = v[r];
                if (RELU) x = fmaxf(x, 0.0f);
                h[(m0 + mt * 16 + quad * 4 + r) * HSTRIDE + ((nt * 16 + col) ^ (r << 3))] = (_Float16)x;
            }
        }
}

__device__ __forceinline__ void mlp_tail_and_out(_Float16* hbuf, float* outstage,
                                                 const half8* __restrict__ wf,
                                                 const float* __restrict__ wsB,
                                                 float* __restrict__ out,
                                                 long base, int t)
{
    const int lane = t & 63;
    const int m0 = (t >> 6) * 32;
    mlp_layer<1, 0,   true>(hbuf, wf, wsB, 0, m0, lane);   // 32 -> 128
    mlp_layer<4, 8,   true>(hbuf, wf, wsB, 1, m0, lane);   // 128 -> 128
    mlp_layer<4, 40,  true>(hbuf, wf, wsB, 2, m0, lane);   // 128 -> 128
    mlp_layer<4, 72,  true>(hbuf, wf, wsB, 3, m0, lane);   // 128 -> 128
    {   // output layer: 128 -> 4 (padded to 16 cols), no ReLU
        const int col = lane & 15, quad = lane >> 4;
        const int sw = (col & 3) << 3;
        half8 a[2][4];
        #pragma unroll
        for (int mt = 0; mt < 2; mt++)
            #pragma unroll
            for (int kt = 0; kt < 4; kt++)
                a[mt][kt] = *(const half8*)&hbuf[(m0 + mt * 16 + col) * HSTRIDE + ((kt * 32 + quad * 8) ^ sw)];
        float bv = wsB[512 + col];
        f32x4 acc[2] = {(f32x4){bv, bv, bv, bv}, (f32x4){bv, bv, bv, bv}};
        half8 b[4];
        #pragma unroll
        for (int kt = 0; kt < 4; kt++)
            b[kt] = wf[(size_t)(104 + kt) * 64 + lane];
        #pragma unroll
        for (int mt = 0; mt < 2; mt++)
            #pragma unroll
            for (int kt = 0; kt < 4; kt++)
                acc[mt] = __builtin_amdgcn_mfma_f32_16x16x32_f16(a[mt][kt], b[kt], acc[mt], 0, 0, 0);
        if (col < 4) {
            #pragma unroll
            for (int mt = 0; mt < 2; mt++)
                #pragma unroll
                for (int r = 0; r < 4; r++)
                    outstage[(m0 + mt * 16 + quad * 4 + r) * 4 + col] = acc[mt][r] * INV_SCALE;
        }
    }
    __syncthreads();
    if (t < 128) {
        f32x4 v = ((const f32x4*)outstage)[t];
        *(f32x4*)(out + (base + t) * 4) = v;
    }
}

// MLP-only kernel: reads level-major feat buffer, stages (swizzled), runs MLP.
__global__ __launch_bounds__(256, 2) void mlp_kernel(
    const _Float16* __restrict__ feat, const half8* __restrict__ wf,
    const float* __restrict__ wsB, float* __restrict__ out, int npts)
{
    __shared__ _Float16 hbuf[128 * HSTRIDE];
    __shared__ float outstage[512];
    const int t = threadIdx.x;
    const long base = (long)blockIdx.x * 128;
    {
        const int l = t >> 4, p0 = (t & 15) * 8;   // 16 lanes/level -> 512B coalesced
        const _Float16* src = feat + ((size_t)l * npts + base + p0) * 2;
        half8 v0 = *(const half8*)src;         // points p0..p0+3 (f0,f1 pairs)
        half8 v1 = *(const half8*)(src + 8);   // points p0+4..p0+7
        #pragma unroll
        for (int j = 0; j < 8; j++) {
            const int p = p0 + j;
            half2 f;
            f[0] = (j < 4) ? v0[2 * j]     : v1[2 * j - 8];
            f[1] = (j < 4) ? v0[2 * j + 1] : v1[2 * j - 7];
            const int c = (2 * l) ^ ((p & 3) << 3);
            *(half2*)&hbuf[p * HSTRIDE + c] = f;
        }
    }
    __syncthreads();
    mlp_tail_and_out(hbuf, outstage, wf, wsB, out, base, t);
}

// ---------------------------------------------------------------------------
// Fallback: Round-1 fused kernel (f32 tables), with swizzled hbuf writes.
// Used only if ws_size can't hold feat+f16 tables.
// ---------------------------------------------------------------------------
__global__ __launch_bounds__(256, 2) void fused_kernel(
    const float* __restrict__ pos, const float* __restrict__ bmn, const float* __restrict__ bmx,
    const float* __restrict__ tables, const half8* __restrict__ wf, const float* __restrict__ wsB,
    float* __restrict__ out)
{
    __shared__ _Float16 hbuf[128 * HSTRIDE];
    __shared__ float outstage[512];
    const int t = threadIdx.x;
    const long base = (long)blockIdx.x * 128;
    {
        const int p = t >> 1, hh = t & 1;
        const long gp = base + p;
        const float b0x = bmn[0], b0y = bmn[1], b0z = bmn[2];
        const float nx = (pos[gp * 3 + 0] - b0x) / (bmx[0] - b0x);
        const float ny = (pos[gp * 3 + 1] - b0y) / (bmx[1] - b0y);
        const float nz = (pos[gp * 3 + 2] - b0z) / (bmx[2] - b0z);
        constexpr float RLO[8] = {16.f, 20.f, 25.f, 32.f, 40.f, 50.f, 64.f, 80.f};
        constexpr float RHI[8] = {101.f, 128.f, 161.f, 203.f, 256.f, 322.f, 406.f, 512.f};
        half8 fa, fb;
        #pragma unroll
        for (int li = 0; li < 8; li++) {
            const float res = hh ? RHI[li] : RLO[li];
            const float* tbl = tables + ((size_t)(hh * 8 + li) << 20);
            float xs = nx * res, ys = ny * res, zs = nz * res;
            float fx = floorf(xs), fy = floorf(ys), fz = floorf(zs);
            unsigned xi = (unsigned)fx, yi = (unsigned)fy, zi = (unsigned)fz;
            float tx = xs - fx, ty = ys - fy, tz = zs - fz;
            unsigned hx[2] = {xi, xi + 1u};
            unsigned hy[2] = {yi * 2654435761u, (yi + 1u) * 2654435761u};
            unsigned hz[2] = {zi * 805459861u, (zi + 1u) * 805459861u};
            float wx[2] = {1.0f - tx, tx}, wy[2] = {1.0f - ty, ty}, wz[2] = {1.0f - tz, tz};
            float a0 = 0.0f, a1 = 0.0f;
            #pragma unroll
            for (int c = 0; c < 8; c++) {
                unsigned hsh = hx[c & 1] ^ hy[(c >> 1) & 1] ^ hz[c >> 2];
                unsigned idx = hsh & TMASK;
                f32x2 f = *(const f32x2*)(tbl + (size_t)idx * 2);
                float w = wx[c & 1] * wy[(c >> 1) & 1] * wz[c >> 2];
                a0 += w * f.x;
                a1 += w * f.y;
            }
            if (li < 4) { fa[2 * li]       = (_Float16)(a0 * SCALE); fa[2 * li + 1]       = (_Float16)(a1 * SCALE); }
            else        { fb[2 * (li - 4)] = (_Float16)(a0 * SCALE); fb[2 * (li - 4) + 1] = (_Float16)(a1 * SCALE); }
        }
        const int sw = (p & 3) << 3;
        *(half8*)&hbuf[p * HSTRIDE + ((hh * 16) ^ sw)]       = fa;
        *(half8*)&hbuf[p * HSTRIDE + (((hh * 16) + 8) ^ sw)] = fb;
    }
    __syncthreads();
    mlp_tail_and_out(hbuf, outstage, wf, wsB, out, base, t);
}

extern "C" void kernel_launch(void* const* d_in, const int* in_sizes, int n_in,
                              void* d_out, int out_size, void* d_ws, size_t ws_size,
                              hipStream_t stream) {
    const float* pos    = (const float*)d_in[0];
    const float* bmn    = (const float*)d_in[1];
    const float* bmx    = (const float*)d_in[2];
    const float* tables = (const float*)d_in[3];
    const float* W0 = (const float*)d_in[4];
    const float* b0 = (const float*)d_in[5];
    const float* W1 = (const float*)d_in[6];
    const float* b1 = (const float*)d_in[7];
    const float* W2 = (const float*)d_in[8];
    const float* b2 = (const float*)d_in[9];
    const float* W3 = (const float*)d_in[10];
    const float* b3 = (const float*)d_in[11];
    const float* Wm = (const float*)d_in[12];
    const float* bm = (const float*)d_in[13];

    const int N = in_sizes[0] / 3;
    const size_t featBytes = (size_t)N * 16 * 4;          // [16][N] f16x2
    const size_t tabBytes  = (size_t)16 * 524288 * 2 * 2; // 32 MB f16
    const size_t need = featBytes + tabBytes + 110592 + 528 * 4;

    if (ws_size >= need && (N % 256) == 0) {
        _Float16* feat = (_Float16*)d_ws;
        _Float16* tabF = (_Float16*)((char*)d_ws + featBytes);
        _Float16* wsW  = (_Float16*)((char*)d_ws + featBytes + tabBytes);
        float*    wsB  = (float*)((char*)d_ws + featBytes + tabBytes + 110592);
        prep_kernel<<<16384 + 30, 256, 0, stream>>>(W0, W1, W2, W3, Wm, b0, b1, b2, b3, bm,
                                                    wsW, wsB, tables, tabF, 16384);
        encode_kernel<<<(N / 256) * 8, 256, 0, stream>>>(pos, bmn, bmx, tabF, feat, N);
        mlp_kernel<<<N / 128, 256, 0, stream>>>(feat, (const half8*)wsW, wsB, (float*)d_out, N);
    } else {
        _Float16* wsW = (_Float16*)d_ws;
        float*    wsB = (float*)((char*)d_ws + 110592);
        prep_kernel<<<30, 256, 0, stream>>>(W0, W1, W2, W3, Wm, b0, b1, b2, b3, bm,
                                            wsW, wsB, tables, (_Float16*)nullptr, 0);
        fused_kernel<<<N / 128, 256, 0, stream>>>(pos, bmn, bmx, tables,
                                                  (const half8*)wsW, wsB, (float*)d_out);
    }
}

// Round 3
// 741.235 us; speedup vs baseline: 1.2468x; 1.1003x over previous
//
#include <hip/hip_runtime.h>

typedef _Float16 half8 __attribute__((ext_vector_type(8)));
typedef _Float16 half4 __attribute__((ext_vector_type(4)));
typedef _Float16 half2 __attribute__((ext_vector_type(2)));
typedef float    f32x4 __attribute__((ext_vector_type(4)));
typedef float    f32x2 __attribute__((ext_vector_type(2)));

#define TMASK ((1u << 19) - 1u)       // T = 2^19
#define HSTRIDE 136                    // 128 + 8 f16 pad; 272B row stride (16B-aligned)
constexpr float SCALE = 65536.0f;      // activation scale: keeps f16 out of subnormal range
constexpr float INV_SCALE = 1.0f / 65536.0f;

// ---------------------------------------------------------------------------
// Prep: (a) convert fp32 tables -> f16 pre-scaled by SCALE (tabBlocks blocks),
//       (b) rearrange fp32 weights into B-fragment-native f16 layout + biases.
// ---------------------------------------------------------------------------
__global__ void prep_kernel(const float* __restrict__ W0, const float* __restrict__ W1,
                            const float* __restrict__ W2, const float* __restrict__ W3,
                            const float* __restrict__ Wm,
                            const float* __restrict__ b0, const float* __restrict__ b1,
                            const float* __restrict__ b2, const float* __restrict__ b3,
                            const float* __restrict__ bm,
                            _Float16* __restrict__ wsW, float* __restrict__ wsB,
                            const float* __restrict__ tables, _Float16* __restrict__ tabF,
                            int tabBlocks)
{
    if ((int)blockIdx.x < tabBlocks) {
        size_t i = (size_t)blockIdx.x * 256 + threadIdx.x;
        f32x4 v = ((const f32x4*)tables)[i];
        half4 o;
        o[0] = (_Float16)(v.x * SCALE);
        o[1] = (_Float16)(v.y * SCALE);
        o[2] = (_Float16)(v.z * SCALE);
        o[3] = (_Float16)(v.w * SCALE);
        ((half4*)tabF)[i] = o;
        return;
    }
    int gid = ((int)blockIdx.x - tabBlocks) * 256 + threadIdx.x;
    if (gid < 6912) {                       // 108 tiles * 64 lanes
        int tile = gid >> 6, lane = gid & 63;
        const float* W; int K, N, toff;
        if (tile < 8)        { W = W0; K = 32;  N = 128; toff = 0;   }
        else if (tile < 40)  { W = W1; K = 128; N = 128; toff = 8;   }
        else if (tile < 72)  { W = W2; K = 128; N = 128; toff = 40;  }
        else if (tile < 104) { W = W3; K = 128; N = 128; toff = 72;  }
        else                 { W = Wm; K = 128; N = 4;   toff = 104; }
        int tt = tile - toff;
        int KT = K >> 5;
        int nt = tt / KT, kt = tt - nt * KT;
        int n = nt * 16 + (lane & 15);
        int kbase = kt * 32 + (lane >> 4) * 8;
        half8 v;
        #pragma unroll
        for (int j = 0; j < 8; j++) {
            int k = kbase + j;
            float w = (n < N) ? W[k * N + n] : 0.0f;
            v[j] = (_Float16)w;
        }
        *(half8*)(wsW + (size_t)gid * 8) = v;
    } else if (gid < 6912 + 528) {
        int i = gid - 6912;
        float v;
        if (i < 512) {
            int layer = i >> 7, n = i & 127;
            const float* b = (layer == 0) ? b0 : (layer == 1) ? b1 : (layer == 2) ? b2 : b3;
            v = b[n] * SCALE;
        } else {
            int n = i - 512;
            v = (n < 4) ? bm[n] * SCALE : 0.0f;
        }
        wsB[i] = v;
    }
}

// ---------------------------------------------------------------------------
// Encode kernel, level-major with XCD affinity (lvl0 = bid&7 -> one table
// pair per XCD L2). MLP-restructured for memory-level parallelism: ALL 16
// corner indices (both levels) are computed first, then all 16 loads issue
// back-to-back; trilinear weights are computed while loads are in flight.
// Level-A accumulation waits at vmcnt(8) with level-B loads still pending.
// ---------------------------------------------------------------------------
__global__ __launch_bounds__(256, 6) void encode_kernel(
    const float* __restrict__ pos, const float* __restrict__ bmn, const float* __restrict__ bmx,
    const _Float16* __restrict__ tab, _Float16* __restrict__ feat, int npts)
{
    const int lvl0 = (int)(blockIdx.x & 7);
    const int p = (int)(blockIdx.x >> 3) * 256 + (int)threadIdx.x;
    const float bx = bmn[0], by = bmn[1], bz = bmn[2];
    const float nx = (pos[(size_t)p * 3 + 0] - bx) / (bmx[0] - bx);
    const float ny = (pos[(size_t)p * 3 + 1] - by) / (bmx[1] - by);
    const float nz = (pos[(size_t)p * 3 + 2] - bz) / (bmx[2] - bz);
    constexpr float RESL[16] = {16.f, 20.f, 25.f, 32.f, 40.f, 50.f, 64.f, 80.f,
                                101.f, 128.f, 161.f, 203.f, 256.f, 322.f, 406.f, 512.f};
    const int l0 = lvl0, l1 = lvl0 + 8;
    const _Float16* tblA = tab + ((size_t)l0 << 20);   // T*2 f16 per level
    const _Float16* tblB = tab + ((size_t)l1 << 20);

    // ---- index computation for BOTH levels (no loads yet) ----
    unsigned idxA[8], idxB[8];
    float txA, tyA, tzA, txB, tyB, tzB;
    {
        const float res = RESL[l0];
        float xs = nx * res, ys = ny * res, zs = nz * res;
        float fx = floorf(xs), fy = floorf(ys), fz = floorf(zs);
        unsigned xi = (unsigned)fx, yi = (unsigned)fy, zi = (unsigned)fz;
        txA = xs - fx; tyA = ys - fy; tzA = zs - fz;
        unsigned hx[2] = {xi, xi + 1u};
        unsigned hy[2] = {yi * 2654435761u, (yi + 1u) * 2654435761u};
        unsigned hz[2] = {zi * 805459861u, (zi + 1u) * 805459861u};
        #pragma unroll
        for (int c = 0; c < 8; c++)
            idxA[c] = (hx[c & 1] ^ hy[(c >> 1) & 1] ^ hz[c >> 2]) & TMASK;
    }
    {
        const float res = RESL[l1];
        float xs = nx * res, ys = ny * res, zs = nz * res;
        float fx = floorf(xs), fy = floorf(ys), fz = floorf(zs);
        unsigned xi = (unsigned)fx, yi = (unsigned)fy, zi = (unsigned)fz;
        txB = xs - fx; tyB = ys - fy; tzB = zs - fz;
        unsigned hx[2] = {xi, xi + 1u};
        unsigned hy[2] = {yi * 2654435761u, (yi + 1u) * 2654435761u};
        unsigned hz[2] = {zi * 805459861u, (zi + 1u) * 805459861u};
        #pragma unroll
        for (int c = 0; c < 8; c++)
            idxB[c] = (hx[c & 1] ^ hy[(c >> 1) & 1] ^ hz[c >> 2]) & TMASK;
    }

    // ---- issue all 16 gathers back-to-back ----
    half2 fvA[8], fvB[8];
    #pragma unroll
    for (int c = 0; c < 8; c++)
        fvA[c] = *(const half2*)(tblA + (size_t)idxA[c] * 2);
    #pragma unroll
    for (int c = 0; c < 8; c++)
        fvB[c] = *(const half2*)(tblB + (size_t)idxB[c] * 2);

    // ---- trilinear weights (VALU overlaps load latency) ----
    float wxA[2] = {1.0f - txA, txA}, wyA[2] = {1.0f - tyA, tyA}, wzA[2] = {1.0f - tzA, tzA};
    float wxB[2] = {1.0f - txB, txB}, wyB[2] = {1.0f - tyB, tyB}, wzB[2] = {1.0f - tzB, tzB};
    float wA[8], wB[8];
    #pragma unroll
    for (int c = 0; c < 8; c++) {
        wA[c] = wxA[c & 1] * wyA[(c >> 1) & 1] * wzA[c >> 2];
        wB[c] = wxB[c & 1] * wyB[(c >> 1) & 1] * wzB[c >> 2];
    }

    float a0 = 0.0f, a1 = 0.0f, b0 = 0.0f, b1 = 0.0f;
    #pragma unroll
    for (int c = 0; c < 8; c++) {       // waits vmcnt(8): B-loads still in flight
        a0 += wA[c] * (float)fvA[c][0];
        a1 += wA[c] * (float)fvA[c][1];
    }
    {
        half2 o; o[0] = (_Float16)a0; o[1] = (_Float16)a1;
        union { half2 h; unsigned u; } cv; cv.h = o;
        __builtin_nontemporal_store(cv.u, (unsigned*)(feat + ((size_t)l0 * npts + p) * 2));
    }
    #pragma unroll
    for (int c = 0; c < 8; c++) {
        b0 += wB[c] * (float)fvB[c][0];
        b1 += wB[c] * (float)fvB[c][1];
    }
    {
        half2 o; o[0] = (_Float16)b0; o[1] = (_Float16)b1;
        union { half2 h; unsigned u; } cv; cv.h = o;
        __builtin_nontemporal_store(cv.u, (unsigned*)(feat + ((size_t)l1 * npts + p) * 2));
    }
}

// ---------------------------------------------------------------------------
// One MLP layer, per-wave, in-place on LDS activations (XOR-swizzled columns).
// A-frag: A[m=lane&15][k=(lane>>4)*8+j]; C/D: col=lane&15, row=(lane>>4)*4+reg.
// ---------------------------------------------------------------------------
template<int KT, int TOFF, bool RELU>
__device__ __forceinline__ void mlp_layer(_Float16* h, const half8* __restrict__ wf,
                                          const float* __restrict__ wsB, int layerIdx,
                                          int m0, int lane)
{
    const int col = lane & 15, quad = lane >> 4;
    const int sw = (col & 3) << 3;
    half8 a[2][KT];
    #pragma unroll
    for (int mt = 0; mt < 2; mt++)
        #pragma unroll
        for (int kt = 0; kt < KT; kt++)
            a[mt][kt] = *(const half8*)&h[(m0 + mt * 16 + col) * HSTRIDE + ((kt * 32 + quad * 8) ^ sw)];

    f32x4 acc[2][8];
    #pragma unroll
    for (int nt = 0; nt < 8; nt++) {
        float bv = wsB[layerIdx * 128 + nt * 16 + col];
        acc[0][nt] = (f32x4){bv, bv, bv, bv};
        acc[1][nt] = (f32x4){bv, bv, bv, bv};
    }
    #pragma unroll
    for (int nt = 0; nt < 8; nt++) {
        half8 b[KT];
        #pragma unroll
        for (int kt = 0; kt < KT; kt++)
            b[kt] = wf[(size_t)(TOFF + nt * KT + kt) * 64 + lane];   // L2-hot global
        #pragma unroll
        for (int mt = 0; mt < 2; mt++)
            #pragma unroll
            for (int kt = 0; kt < KT; kt++)
                acc[mt][nt] = __builtin_amdgcn_mfma_f32_16x16x32_f16(a[mt][kt], b[kt], acc[mt][nt], 0, 0, 0);
    }
    #pragma unroll
    for (int mt = 0; mt < 2; mt++)
        #pragma unroll
        for (int nt = 0; nt < 8; nt++) {
            f32x4 v = acc[mt][nt];
            #pragma unroll
            for (int r = 0; r < 4; r++) {
                float x = v[r];
                if (RELU) x = fmaxf(x, 0.0f);
                h[(m0 + mt * 16 + quad * 4 + r) * HSTRIDE + ((nt * 16 + col) ^ (r << 3))] = (_Float16)x;
            }
        }
}

__device__ __forceinline__ void mlp_tail_and_out(_Float16* hbuf, float* outstage,
                                                 const half8* __restrict__ wf,
                                                 const float* __restrict__ wsB,
                                                 float* __restrict__ out,
                                                 long base, int t)
{
    const int lane = t & 63;
    const int m0 = (t >> 6) * 32;
    mlp_layer<1, 0,   true>(hbuf, wf, wsB, 0, m0, lane);   // 32 -> 128
    mlp_layer<4, 8,   true>(hbuf, wf, wsB, 1, m0, lane);   // 128 -> 128
    mlp_layer<4, 40,  true>(hbuf, wf, wsB, 2, m0, lane);   // 128 -> 128
    mlp_layer<4, 72,  true>(hbuf, wf, wsB, 3, m0, lane);   // 128 -> 128
    {   // output layer: 128 -> 4 (padded to 16 cols), no ReLU
        const int col = lane & 15, quad = lane >> 4;
        const int sw = (col & 3) << 3;
        half8 a[2][4];
        #pragma unroll
        for (int mt = 0; mt < 2; mt++)
            #pragma unroll
            for (int kt = 0; kt < 4; kt++)
                a[mt][kt] = *(const half8*)&hbuf[(m0 + mt * 16 + col) * HSTRIDE + ((kt * 32 + quad * 8) ^ sw)];
        float bv = wsB[512 + col];
        f32x4 acc[2] = {(f32x4){bv, bv, bv, bv}, (f32x4){bv, bv, bv, bv}};
        half8 b[4];
        #pragma unroll
        for (int kt = 0; kt < 4; kt++)
            b[kt] = wf[(size_t)(104 + kt) * 64 + lane];
        #pragma unroll
        for (int mt = 0; mt < 2; mt++)
            #pragma unroll
            for (int kt = 0; kt < 4; kt++)
                acc[mt] = __builtin_amdgcn_mfma_f32_16x16x32_f16(a[mt][kt], b[kt], acc[mt], 0, 0, 0);
        if (col < 4) {
            #pragma unroll
            for (int mt = 0; mt < 2; mt++)
                #pragma unroll
                for (int r = 0; r < 4; r++)
                    outstage[(m0 + mt * 16 + quad * 4 + r) * 4 + col] = acc[mt][r] * INV_SCALE;
        }
    }
    __syncthreads();
    if (t < 128) {
        f32x4 v = ((const f32x4*)outstage)[t];
        *(f32x4*)(out + (base + t) * 4) = v;
    }
}

// MLP-only kernel: reads level-major feat buffer, stages (swizzled), runs MLP.
__global__ __launch_bounds__(256, 2) void mlp_kernel(
    const _Float16* __restrict__ feat, const half8* __restrict__ wf,
    const float* __restrict__ wsB, float* __restrict__ out, int npts)
{
    __shared__ _Float16 hbuf[128 * HSTRIDE];
    __shared__ float outstage[512];
    const int t = threadIdx.x;
    const long base = (long)blockIdx.x * 128;
    {
        const int l = t >> 4, p0 = (t & 15) * 8;   // 16 lanes/level -> 512B coalesced
        const _Float16* src = feat + ((size_t)l * npts + base + p0) * 2;
        half8 v0 = *(const half8*)src;         // points p0..p0+3 (f0,f1 pairs)
        half8 v1 = *(const half8*)(src + 8);   // points p0+4..p0+7
        #pragma unroll
        for (int j = 0; j < 8; j++) {
            const int p = p0 + j;
            half2 f;
            f[0] = (j < 4) ? v0[2 * j]     : v1[2 * j - 8];
            f[1] = (j < 4) ? v0[2 * j + 1] : v1[2 * j - 7];
            const int c = (2 * l) ^ ((p & 3) << 3);
            *(half2*)&hbuf[p * HSTRIDE + c] = f;
        }
    }
    __syncthreads();
    mlp_tail_and_out(hbuf, outstage, wf, wsB, out, base, t);
}

// ---------------------------------------------------------------------------
// Fallback: fused single-kernel path (f32 tables), used only if ws too small.
// ---------------------------------------------------------------------------
__global__ __launch_bounds__(256, 2) void fused_kernel(
    const float* __restrict__ pos, const float* __restrict__ bmn, const float* __restrict__ bmx,
    const float* __restrict__ tables, const half8* __restrict__ wf, const float* __restrict__ wsB,
    float* __restrict__ out)
{
    __shared__ _Float16 hbuf[128 * HSTRIDE];
    __shared__ float outstage[512];
    const int t = threadIdx.x;
    const long base = (long)blockIdx.x * 128;
    {
        const int p = t >> 1, hh = t & 1;
        const long gp = base + p;
        const float b0x = bmn[0], b0y = bmn[1], b0z = bmn[2];
        const float nx = (pos[gp * 3 + 0] - b0x) / (bmx[0] - b0x);
        const float ny = (pos[gp * 3 + 1] - b0y) / (bmx[1] - b0y);
        const float nz = (pos[gp * 3 + 2] - b0z) / (bmx[2] - b0z);
        constexpr float RLO[8] = {16.f, 20.f, 25.f, 32.f, 40.f, 50.f, 64.f, 80.f};
        constexpr float RHI[8] = {101.f, 128.f, 161.f, 203.f, 256.f, 322.f, 406.f, 512.f};
        half8 fa, fb;
        #pragma unroll
        for (int li = 0; li < 8; li++) {
            const float res = hh ? RHI[li] : RLO[li];
            const float* tbl = tables + ((size_t)(hh * 8 + li) << 20);
            float xs = nx * res, ys = ny * res, zs = nz * res;
            float fx = floorf(xs), fy = floorf(ys), fz = floorf(zs);
            unsigned xi = (unsigned)fx, yi = (unsigned)fy, zi = (unsigned)fz;
            float tx = xs - fx, ty = ys - fy, tz = zs - fz;
            unsigned hx[2] = {xi, xi + 1u};
            unsigned hy[2] = {yi * 2654435761u, (yi + 1u) * 2654435761u};
            unsigned hz[2] = {zi * 805459861u, (zi + 1u) * 805459861u};
            float wx[2] = {1.0f - tx, tx}, wy[2] = {1.0f - ty, ty}, wz[2] = {1.0f - tz, tz};
            float a0 = 0.0f, a1 = 0.0f;
            #pragma unroll
            for (int c = 0; c < 8; c++) {
                unsigned hsh = hx[c & 1] ^ hy[(c >> 1) & 1] ^ hz[c >> 2];
                unsigned idx = hsh & TMASK;
                f32x2 f = *(const f32x2*)(tbl + (size_t)idx * 2);
                float w = wx[c & 1] * wy[(c >> 1) & 1] * wz[c >> 2];
                a0 += w * f.x;
                a1 += w * f.y;
            }
            if (li < 4) { fa[2 * li]       = (_Float16)(a0 * SCALE); fa[2 * li + 1]       = (_Float16)(a1 * SCALE); }
            else        { fb[2 * (li - 4)] = (_Float16)(a0 * SCALE); fb[2 * (li - 4) + 1] = (_Float16)(a1 * SCALE); }
        }
        const int sw = (p & 3) << 3;
        *(half8*)&hbuf[p * HSTRIDE + ((hh * 16) ^ sw)]       = fa;
        *(half8*)&hbuf[p * HSTRIDE + (((hh * 16) + 8) ^ sw)] = fb;
    }
    __syncthreads();
    mlp_tail_and_out(hbuf, outstage, wf, wsB, out, base, t);
}

extern "C" void kernel_launch(void* const* d_in, const int* in_sizes, int n_in,
                              void* d_out, int out_size, void* d_ws, size_t ws_size,
                              hipStream_t stream) {
    const float* pos    = (const float*)d_in[0];
    const float* bmn    = (const float*)d_in[1];
    const float* bmx    = (const float*)d_in[2];
    const float* tables = (const float*)d_in[3];
    const float* W0 = (const float*)d_in[4];
    const float* b0 = (const float*)d_in[5];
    const float* W1 = (const float*)d_in[6];
    const float* b1 = (const float*)d_in[7];
    const float* W2 = (const float*)d_in[8];
    const float* b2 = (const float*)d_in[9];
    const float* W3 = (const float*)d_in[10];
    const float* b3 = (const float*)d_in[11];
    const float* Wm = (const float*)d_in[12];
    const float* bm = (const float*)d_in[13];

    const int N = in_sizes[0] / 3;
    const size_t featBytes = (size_t)N * 16 * 4;          // [16][N] f16x2
    const size_t tabBytes  = (size_t)16 * 524288 * 2 * 2; // 32 MB f16
    const size_t need = featBytes + tabBytes + 110592 + 528 * 4;

    if (ws_size >= need && (N % 256) == 0) {
        _Float16* feat = (_Float16*)d_ws;
        _Float16* tabF = (_Float16*)((char*)d_ws + featBytes);
        _Float16* wsW  = (_Float16*)((char*)d_ws + featBytes + tabBytes);
        float*    wsB  = (float*)((char*)d_ws + featBytes + tabBytes + 110592);
        prep_kernel<<<16384 + 30, 256, 0, stream>>>(W0, W1, W2, W3, Wm, b0, b1, b2, b3, bm,
                                                    wsW, wsB, tables, tabF, 16384);
        encode_kernel<<<(N / 256) * 8, 256, 0, stream>>>(pos, bmn, bmx, tabF, feat, N);
        mlp_kernel<<<N / 128, 256, 0, stream>>>(feat, (const half8*)wsW, wsB, (float*)d_out, N);
    } else {
        _Float16* wsW = (_Float16*)d_ws;
        float*    wsB = (float*)((char*)d_ws + 110592);
        prep_kernel<<<30, 256, 0, stream>>>(W0, W1, W2, W3, Wm, b0, b1, b2, b3, bm,
                                            wsW, wsB, tables, (_Float16*)nullptr, 0);
        fused_kernel<<<N / 128, 256, 0, stream>>>(pos, bmn, bmx, tables,
                                                  (const half8*)wsW, wsB, (float*)d_out);
    }
}

// Round 4
// 701.315 us; speedup vs baseline: 1.3178x; 1.0569x over previous
//
#include <hip/hip_runtime.h>

typedef _Float16 half8 __attribute__((ext_vector_type(8)));
typedef _Float16 half4 __attribute__((ext_vector_type(4)));
typedef _Float16 half2 __attribute__((ext_vector_type(2)));
typedef float    f32x4 __attribute__((ext_vector_type(4)));
typedef float    f32x2 __attribute__((ext_vector_type(2)));
typedef unsigned u32x2 __attribute__((ext_vector_type(2)));

#define TMASK ((1u << 19) - 1u)       // T = 2^19
#define HSTRIDE 136                    // 128 + 8 f16 pad; 272B row stride (16B-aligned)
constexpr float SCALE = 65536.0f;      // activation scale: keeps f16 out of subnormal range
constexpr float INV_SCALE = 1.0f / 65536.0f;

// ---------------------------------------------------------------------------
// Prep: (a) fp32 tables -> f16 pre-scaled by SCALE, (b) weights -> B-frag f16.
// ---------------------------------------------------------------------------
__global__ void prep_kernel(const float* __restrict__ W0, const float* __restrict__ W1,
                            const float* __restrict__ W2, const float* __restrict__ W3,
                            const float* __restrict__ Wm,
                            const float* __restrict__ b0, const float* __restrict__ b1,
                            const float* __restrict__ b2, const float* __restrict__ b3,
                            const float* __restrict__ bm,
                            _Float16* __restrict__ wsW, float* __restrict__ wsB,
                            const float* __restrict__ tables, _Float16* __restrict__ tabF,
                            int tabBlocks)
{
    if ((int)blockIdx.x < tabBlocks) {
        size_t i = (size_t)blockIdx.x * 256 + threadIdx.x;
        f32x4 v = ((const f32x4*)tables)[i];
        half4 o;
        o[0] = (_Float16)(v.x * SCALE);
        o[1] = (_Float16)(v.y * SCALE);
        o[2] = (_Float16)(v.z * SCALE);
        o[3] = (_Float16)(v.w * SCALE);
        ((half4*)tabF)[i] = o;
        return;
    }
    int gid = ((int)blockIdx.x - tabBlocks) * 256 + threadIdx.x;
    if (gid < 6912) {                       // 108 tiles * 64 lanes
        int tile = gid >> 6, lane = gid & 63;
        const float* W; int K, N, toff;
        if (tile < 8)        { W = W0; K = 32;  N = 128; toff = 0;   }
        else if (tile < 40)  { W = W1; K = 128; N = 128; toff = 8;   }
        else if (tile < 72)  { W = W2; K = 128; N = 128; toff = 40;  }
        else if (tile < 104) { W = W3; K = 128; N = 128; toff = 72;  }
        else                 { W = Wm; K = 128; N = 4;   toff = 104; }
        int tt = tile - toff;
        int KT = K >> 5;
        int nt = tt / KT, kt = tt - nt * KT;
        int n = nt * 16 + (lane & 15);
        int kbase = kt * 32 + (lane >> 4) * 8;
        half8 v;
        #pragma unroll
        for (int j = 0; j < 8; j++) {
            int k = kbase + j;
            float w = (n < N) ? W[k * N + n] : 0.0f;
            v[j] = (_Float16)w;
        }
        *(half8*)(wsW + (size_t)gid * 8) = v;
    } else if (gid < 6912 + 528) {
        int i = gid - 6912;
        float v;
        if (i < 512) {
            int layer = i >> 7, n = i & 127;
            const float* b = (layer == 0) ? b0 : (layer == 1) ? b1 : (layer == 2) ? b2 : b3;
            v = b[n] * SCALE;
        } else {
            int n = i - 512;
            v = (n < 4) ? bm[n] * SCALE : 0.0f;
        }
        wsB[i] = v;
    }
}

// ---------------------------------------------------------------------------
// Encode kernel, level-major with XCD affinity (lvl0 = bid&7).
// Request reduction: x-prime is 1, so for even x, idx(x+1) = idx(x)^1 -> the
// x-corner pair shares one aligned 8B table slot. Per level: 4 unconditional
// 8B slot loads (even-x corners) + 4 masked 4B loads (only when x0 is odd).
// Avg 6 requests/level vs 8 -> -25% L2 requests (encode is L2-request-bound:
// R3 measured 15.2 req/cy/XCD = the 16-channel tag ceiling).
// ---------------------------------------------------------------------------
__global__ __launch_bounds__(256, 4) void encode_kernel(
    const float* __restrict__ pos, const float* __restrict__ bmn, const float* __restrict__ bmx,
    const _Float16* __restrict__ tab, _Float16* __restrict__ feat, int npts)
{
    const int lvl0 = (int)(blockIdx.x & 7);
    const int p = (int)(blockIdx.x >> 3) * 256 + (int)threadIdx.x;
    const float bx = bmn[0], by = bmn[1], bz = bmn[2];
    const float nx = (pos[(size_t)p * 3 + 0] - bx) / (bmx[0] - bx);
    const float ny = (pos[(size_t)p * 3 + 1] - by) / (bmx[1] - by);
    const float nz = (pos[(size_t)p * 3 + 2] - bz) / (bmx[2] - bz);
    constexpr float RESL[16] = {16.f, 20.f, 25.f, 32.f, 40.f, 50.f, 64.f, 80.f,
                                101.f, 128.f, 161.f, 203.f, 256.f, 322.f, 406.f, 512.f};
    const int l0 = lvl0, l1 = lvl0 + 8;
    const _Float16* tblA = tab + ((size_t)l0 << 20);
    const _Float16* tblB = tab + ((size_t)l1 << 20);

    // ---- index computation for BOTH levels ----
    unsigned idxAE[4], idxAO[4], idxBE[4], idxBO[4];
    bool oddA, oddB;
    float txA, tyA, tzA, txB, tyB, tzB;
    {
        const float res = RESL[l0];
        float xs = nx * res, ys = ny * res, zs = nz * res;
        float fx = floorf(xs), fy = floorf(ys), fz = floorf(zs);
        unsigned xi = (unsigned)fx, yi = (unsigned)fy, zi = (unsigned)fz;
        txA = xs - fx; tyA = ys - fy; tzA = zs - fz;
        unsigned hy0 = yi * 2654435761u, hy1 = (yi + 1u) * 2654435761u;
        unsigned hz0 = zi * 805459861u,  hz1 = (zi + 1u) * 805459861u;
        unsigned hyz[4] = {hy0 ^ hz0, hy1 ^ hz0, hy0 ^ hz1, hy1 ^ hz1};
        unsigned e = (xi + 1u) & ~1u;      // even member of {xi, xi+1}
        unsigned o = xi | 1u;              // odd member
        oddA = (xi & 1u) != 0u;
        #pragma unroll
        for (int g = 0; g < 4; g++) {
            idxAE[g] = (e ^ hyz[g]) & TMASK;
            idxAO[g] = (o ^ hyz[g]) & TMASK;
        }
    }
    {
        const float res = RESL[l1];
        float xs = nx * res, ys = ny * res, zs = nz * res;
        float fx = floorf(xs), fy = floorf(ys), fz = floorf(zs);
        unsigned xi = (unsigned)fx, yi = (unsigned)fy, zi = (unsigned)fz;
        txB = xs - fx; tyB = ys - fy; tzB = zs - fz;
        unsigned hy0 = yi * 2654435761u, hy1 = (yi + 1u) * 2654435761u;
        unsigned hz0 = zi * 805459861u,  hz1 = (zi + 1u) * 805459861u;
        unsigned hyz[4] = {hy0 ^ hz0, hy1 ^ hz0, hy0 ^ hz1, hy1 ^ hz1};
        unsigned e = (xi + 1u) & ~1u;
        unsigned o = xi | 1u;
        oddB = (xi & 1u) != 0u;
        #pragma unroll
        for (int g = 0; g < 4; g++) {
            idxBE[g] = (e ^ hyz[g]) & TMASK;
            idxBO[g] = (o ^ hyz[g]) & TMASK;
        }
    }

    // ---- unconditional 8B slot loads (cover even-x corner + its ^1 neighbor) ----
    u32x2 sA[4], sB[4];
    #pragma unroll
    for (int g = 0; g < 4; g++)
        sA[g] = *(const u32x2*)(tblA + (size_t)(idxAE[g] & ~1u) * 2);
    #pragma unroll
    for (int g = 0; g < 4; g++)
        sB[g] = *(const u32x2*)(tblB + (size_t)(idxBE[g] & ~1u) * 2);

    // ---- masked 4B loads for odd-x0 lanes ----
    half2 oAv[4], oBv[4];
    if (oddA) {
        #pragma unroll
        for (int g = 0; g < 4; g++)
            oAv[g] = *(const half2*)(tblA + (size_t)idxAO[g] * 2);
    }
    if (oddB) {
        #pragma unroll
        for (int g = 0; g < 4; g++)
            oBv[g] = *(const half2*)(tblB + (size_t)idxBO[g] * 2);
    }

    // ---- trilinear weights (overlap load latency) ----
    float wyzA[4] = {(1.0f - tyA) * (1.0f - tzA), tyA * (1.0f - tzA),
                     (1.0f - tyA) * tzA,          tyA * tzA};
    float wyzB[4] = {(1.0f - tyB) * (1.0f - tzB), tyB * (1.0f - tzB),
                     (1.0f - tyB) * tzB,          tyB * tzB};

    float a0 = 0.0f, a1 = 0.0f, b0 = 0.0f, b1 = 0.0f;
    #pragma unroll
    for (int g = 0; g < 4; g++) {
        union { unsigned u; half2 h; } lo, hi;
        lo.u = sA[g][0]; hi.u = sA[g][1];
        bool pe = (idxAE[g] & 1u) != 0u;
        half2 fe  = pe ? hi.h : lo.h;      // feature at x = even e
        half2 fe1 = pe ? lo.h : hi.h;      // feature at x = e^1 = e+1
        half2 fx0 = oddA ? oAv[g] : fe;    // x = x0
        half2 fx1 = oddA ? fe : fe1;       // x = x0+1
        float w0 = wyzA[g] * (1.0f - txA), w1 = wyzA[g] * txA;
        a0 += w0 * (float)fx0[0] + w1 * (float)fx1[0];
        a1 += w0 * (float)fx0[1] + w1 * (float)fx1[1];
    }
    {
        half2 ov; ov[0] = (_Float16)a0; ov[1] = (_Float16)a1;
        union { half2 h; unsigned u; } cv; cv.h = ov;
        __builtin_nontemporal_store(cv.u, (unsigned*)(feat + ((size_t)l0 * npts + p) * 2));
    }
    #pragma unroll
    for (int g = 0; g < 4; g++) {
        union { unsigned u; half2 h; } lo, hi;
        lo.u = sB[g][0]; hi.u = sB[g][1];
        bool pe = (idxBE[g] & 1u) != 0u;
        half2 fe  = pe ? hi.h : lo.h;
        half2 fe1 = pe ? lo.h : hi.h;
        half2 fx0 = oddB ? oBv[g] : fe;
        half2 fx1 = oddB ? fe : fe1;
        float w0 = wyzB[g] * (1.0f - txB), w1 = wyzB[g] * txB;
        b0 += w0 * (float)fx0[0] + w1 * (float)fx1[0];
        b1 += w0 * (float)fx0[1] + w1 * (float)fx1[1];
    }
    {
        half2 ov; ov[0] = (_Float16)b0; ov[1] = (_Float16)b1;
        union { half2 h; unsigned u; } cv; cv.h = ov;
        __builtin_nontemporal_store(cv.u, (unsigned*)(feat + ((size_t)l1 * npts + p) * 2));
    }
}

// ---------------------------------------------------------------------------
// One MLP layer, per-wave, in-place on LDS activations (XOR-swizzled cols).
// A-frag: A[m=lane&15][k=(lane>>4)*8+j]; C/D: col=lane&15, row=(lane>>4)*4+reg.
// ---------------------------------------------------------------------------
template<int KT, int TOFF, bool RELU>
__device__ __forceinline__ void mlp_layer(_Float16* h, const half8* __restrict__ wf,
                                          const float* __restrict__ wsB, int layerIdx,
                                          int m0, int lane)
{
    const int col = lane & 15, quad = lane >> 4;
    const int sw = (col & 3) << 3;
    half8 a[2][KT];
    #pragma unroll
    for (int mt = 0; mt < 2; mt++)
        #pragma unroll
        for (int kt = 0; kt < KT; kt++)
            a[mt][kt] = *(const half8*)&h[(m0 + mt * 16 + col) * HSTRIDE + ((kt * 32 + quad * 8) ^ sw)];

    f32x4 acc[2][8];
    #pragma unroll
    for (int nt = 0; nt < 8; nt++) {
        float bv = wsB[layerIdx * 128 + nt * 16 + col];
        acc[0][nt] = (f32x4){bv, bv, bv, bv};
        acc[1][nt] = (f32x4){bv, bv, bv, bv};
    }
    #pragma unroll
    for (int nt = 0; nt < 8; nt++) {
        half8 b[KT];
        #pragma unroll
        for (int kt = 0; kt < KT; kt++)
            b[kt] = wf[(size_t)(TOFF + nt * KT + kt) * 64 + lane];   // L2-hot global
        #pragma unroll
        for (int mt = 0; mt < 2; mt++)
            #pragma unroll
            for (int kt = 0; kt < KT; kt++)
                acc[mt][nt] = __builtin_amdgcn_mfma_f32_16x16x32_f16(a[mt][kt], b[kt], acc[mt][nt], 0, 0, 0);
    }
    #pragma unroll
    for (int mt = 0; mt < 2; mt++)
        #pragma unroll
        for (int nt = 0; nt < 8; nt++) {
            f32x4 v = acc[mt][nt];
            #pragma unroll
            for (int r = 0; r < 4; r++) {
                float x = v[r];
                if (RELU) x = fmaxf(x, 0.0f);
                h[(m0 + mt * 16 + quad * 4 + r) * HSTRIDE + ((nt * 16 + col) ^ (r << 3))] = (_Float16)x;
            }
        }
}

template<int PTS>
__device__ __forceinline__ void mlp_tail_and_out(_Float16* hbuf, float* outstage,
                                                 const half8* __restrict__ wf,
                                                 const float* __restrict__ wsB,
                                                 float* __restrict__ out,
                                                 long base, int t)
{
    const int lane = t & 63;
    const int m0 = (t >> 6) * 32;
    mlp_layer<1, 0,   true>(hbuf, wf, wsB, 0, m0, lane);   // 32 -> 128
    mlp_layer<4, 8,   true>(hbuf, wf, wsB, 1, m0, lane);   // 128 -> 128
    mlp_layer<4, 40,  true>(hbuf, wf, wsB, 2, m0, lane);   // 128 -> 128
    mlp_layer<4, 72,  true>(hbuf, wf, wsB, 3, m0, lane);   // 128 -> 128
    {   // output layer: 128 -> 4 (padded to 16 cols), no ReLU
        const int col = lane & 15, quad = lane >> 4;
        const int sw = (col & 3) << 3;
        half8 a[2][4];
        #pragma unroll
        for (int mt = 0; mt < 2; mt++)
            #pragma unroll
            for (int kt = 0; kt < 4; kt++)
                a[mt][kt] = *(const half8*)&hbuf[(m0 + mt * 16 + col) * HSTRIDE + ((kt * 32 + quad * 8) ^ sw)];
        float bv = wsB[512 + col];
        f32x4 acc[2] = {(f32x4){bv, bv, bv, bv}, (f32x4){bv, bv, bv, bv}};
        half8 b[4];
        #pragma unroll
        for (int kt = 0; kt < 4; kt++)
            b[kt] = wf[(size_t)(104 + kt) * 64 + lane];
        #pragma unroll
        for (int mt = 0; mt < 2; mt++)
            #pragma unroll
            for (int kt = 0; kt < 4; kt++)
                acc[mt] = __builtin_amdgcn_mfma_f32_16x16x32_f16(a[mt][kt], b[kt], acc[mt], 0, 0, 0);
        if (col < 4) {
            #pragma unroll
            for (int mt = 0; mt < 2; mt++)
                #pragma unroll
                for (int r = 0; r < 4; r++)
                    outstage[(m0 + mt * 16 + quad * 4 + r) * 4 + col] = acc[mt][r] * INV_SCALE;
        }
    }
    __syncthreads();
    if (t < PTS) {
        f32x4 v = ((const f32x4*)outstage)[t];
        *(f32x4*)(out + (base + t) * 4) = v;
    }
}

// MLP-only kernel: 512 threads / 256 points per block -> 16 waves/CU
// (2 blocks x 8 waves; LDS 73.7 KB/block) for 2x latency hiding on the
// per-layer ds_read -> MFMA -> ds_write chains.
__global__ __launch_bounds__(512, 4) void mlp_kernel(
    const _Float16* __restrict__ feat, const half8* __restrict__ wf,
    const float* __restrict__ wsB, float* __restrict__ out, int npts)
{
    __shared__ _Float16 hbuf[256 * HSTRIDE];
    __shared__ float outstage[1024];
    const int t = threadIdx.x;
    const long base = (long)blockIdx.x * 256;
    {
        const int l = t >> 5, p0 = (t & 31) * 8;   // 32 lanes/level, coalesced
        const _Float16* src = feat + ((size_t)l * npts + base + p0) * 2;
        half8 v0 = *(const half8*)src;         // points p0..p0+3 (f0,f1 pairs)
        half8 v1 = *(const half8*)(src + 8);   // points p0+4..p0+7
        #pragma unroll
        for (int j = 0; j < 8; j++) {
            const int p = p0 + j;
            half2 f;
            f[0] = (j < 4) ? v0[2 * j]     : v1[2 * j - 8];
            f[1] = (j < 4) ? v0[2 * j + 1] : v1[2 * j - 7];
            const int c = (2 * l) ^ ((p & 3) << 3);
            *(half2*)&hbuf[p * HSTRIDE + c] = f;
        }
    }
    __syncthreads();
    mlp_tail_and_out<256>(hbuf, outstage, wf, wsB, out, base, t);
}

// ---------------------------------------------------------------------------
// Fallback: fused single-kernel path (f32 tables), used only if ws too small.
// ---------------------------------------------------------------------------
__global__ __launch_bounds__(256, 2) void fused_kernel(
    const float* __restrict__ pos, const float* __restrict__ bmn, const float* __restrict__ bmx,
    const float* __restrict__ tables, const half8* __restrict__ wf, const float* __restrict__ wsB,
    float* __restrict__ out)
{
    __shared__ _Float16 hbuf[128 * HSTRIDE];
    __shared__ float outstage[512];
    const int t = threadIdx.x;
    const long base = (long)blockIdx.x * 128;
    {
        const int p = t >> 1, hh = t & 1;
        const long gp = base + p;
        const float b0x = bmn[0], b0y = bmn[1], b0z = bmn[2];
        const float nx = (pos[gp * 3 + 0] - b0x) / (bmx[0] - b0x);
        const float ny = (pos[gp * 3 + 1] - b0y) / (bmx[1] - b0y);
        const float nz = (pos[gp * 3 + 2] - b0z) / (bmx[2] - b0z);
        constexpr float RLO[8] = {16.f, 20.f, 25.f, 32.f, 40.f, 50.f, 64.f, 80.f};
        constexpr float RHI[8] = {101.f, 128.f, 161.f, 203.f, 256.f, 322.f, 406.f, 512.f};
        half8 fa, fb;
        #pragma unroll
        for (int li = 0; li < 8; li++) {
            const float res = hh ? RHI[li] : RLO[li];
            const float* tbl = tables + ((size_t)(hh * 8 + li) << 20);
            float xs = nx * res, ys = ny * res, zs = nz * res;
            float fx = floorf(xs), fy = floorf(ys), fz = floorf(zs);
            unsigned xi = (unsigned)fx, yi = (unsigned)fy, zi = (unsigned)fz;
            float tx = xs - fx, ty = ys - fy, tz = zs - fz;
            unsigned hx[2] = {xi, xi + 1u};
            unsigned hy[2] = {yi * 2654435761u, (yi + 1u) * 2654435761u};
            unsigned hz[2] = {zi * 805459861u, (zi + 1u) * 805459861u};
            float wx[2] = {1.0f - tx, tx}, wy[2] = {1.0f - ty, ty}, wz[2] = {1.0f - tz, tz};
            float a0 = 0.0f, a1 = 0.0f;
            #pragma unroll
            for (int c = 0; c < 8; c++) {
                unsigned hsh = hx[c & 1] ^ hy[(c >> 1) & 1] ^ hz[c >> 2];
                unsigned idx = hsh & TMASK;
                f32x2 f = *(const f32x2*)(tbl + (size_t)idx * 2);
                float w = wx[c & 1] * wy[(c >> 1) & 1] * wz[c >> 2];
                a0 += w * f.x;
                a1 += w * f.y;
            }
            if (li < 4) { fa[2 * li]       = (_Float16)(a0 * SCALE); fa[2 * li + 1]       = (_Float16)(a1 * SCALE); }
            else        { fb[2 * (li - 4)] = (_Float16)(a0 * SCALE); fb[2 * (li - 4) + 1] = (_Float16)(a1 * SCALE); }
        }
        const int sw = (p & 3) << 3;
        *(half8*)&hbuf[p * HSTRIDE + ((hh * 16) ^ sw)]       = fa;
        *(half8*)&hbuf[p * HSTRIDE + (((hh * 16) + 8) ^ sw)] = fb;
    }
    __syncthreads();
    mlp_tail_and_out<128>(hbuf, outstage, wf, wsB, out, base, t);
}

extern "C" void kernel_launch(void* const* d_in, const int* in_sizes, int n_in,
                              void* d_out, int out_size, void* d_ws, size_t ws_size,
                              hipStream_t stream) {
    const float* pos    = (const float*)d_in[0];
    const float* bmn    = (const float*)d_in[1];
    const float* bmx    = (const float*)d_in[2];
    const float* tables = (const float*)d_in[3];
    const float* W0 = (const float*)d_in[4];
    const float* b0 = (const float*)d_in[5];
    const float* W1 = (const float*)d_in[6];
    const float* b1 = (const float*)d_in[7];
    const float* W2 = (const float*)d_in[8];
    const float* b2 = (const float*)d_in[9];
    const float* W3 = (const float*)d_in[10];
    const float* b3 = (const float*)d_in[11];
    const float* Wm = (const float*)d_in[12];
    const float* bm = (const float*)d_in[13];

    const int N = in_sizes[0] / 3;
    const size_t featBytes = (size_t)N * 16 * 4;          // [16][N] f16x2
    const size_t tabBytes  = (size_t)16 * 524288 * 2 * 2; // 32 MB f16
    const size_t need = featBytes + tabBytes + 110592 + 528 * 4;

    if (ws_size >= need && (N % 256) == 0) {
        _Float16* feat = (_Float16*)d_ws;
        _Float16* tabF = (_Float16*)((char*)d_ws + featBytes);
        _Float16* wsW  = (_Float16*)((char*)d_ws + featBytes + tabBytes);
        float*    wsB  = (float*)((char*)d_ws + featBytes + tabBytes + 110592);
        prep_kernel<<<16384 + 30, 256, 0, stream>>>(W0, W1, W2, W3, Wm, b0, b1, b2, b3, bm,
                                                    wsW, wsB, tables, tabF, 16384);
        encode_kernel<<<(N / 256) * 8, 256, 0, stream>>>(pos, bmn, bmx, tabF, feat, N);
        mlp_kernel<<<N / 256, 512, 0, stream>>>(feat, (const half8*)wsW, wsB, (float*)d_out, N);
    } else {
        _Float16* wsW = (_Float16*)d_ws;
        float*    wsB = (float*)((char*)d_ws + 110592);
        prep_kernel<<<30, 256, 0, stream>>>(W0, W1, W2, W3, Wm, b0, b1, b2, b3, bm,
                                            wsW, wsB, tables, (_Float16*)nullptr, 0);
        fused_kernel<<<N / 128, 256, 0, stream>>>(pos, bmn, bmx, tables,
                                                  (const half8*)wsW, wsB, (float*)d_out);
    }
}